// Round 5
// baseline (531.524 us; speedup 1.0000x reference)
//
#include <hip/hip_runtime.h>
#include <stdint.h>

// CoarseMatching on MI355X, round 7.
// conf[n,l,s] = softmax_l(sim)*softmax_s(sim), sim = <f0[l],f1[s]>/25.6.
// Round-7 theory: rounds 4-6 all ~154us because per-wave register state
// (a[3][8]=96 + acc=36 in the unified VGPR/AGPR file + 84 VGPR = ~216 regs)
// capped occupancy at 2 waves/SIMD (measured 24%) -- latency-bound.
// Fix: DON'T keep X fragments resident; reload 3 xa frags per k from L1/L2
// (X chunk is 73.7KB/block, cache-hot), pipeline yb loads one k ahead.
// Register budget ~112 -> __launch_bounds__(192,4) = 4 waves/SIMD.
// Chunk 240->144 (grid 25x25x4=2500) for ~92%-full scheduler rounds.
// Still barrier-free (one __syncthreads per kernel for col-partial merge).

typedef _Float16 f16;
typedef _Float16 f16x8 __attribute__((ext_vector_type(8)));
typedef float f32x4 __attribute__((ext_vector_type(4)));

#define N_B 4
#define L_DIM 3600
#define S_DIM 3600
#define C_DIM 256

// GEMM tiling (both passes): 3 waves x 48 rows = 144 rows/block; 48 cols/iter;
// 144-col chunks. grid 25 x 25 x 4 = 2500 blocks.
#define P1_THREADS 192
#define P1_BM 144
#define P1_BN 48
#define P1_ITERS 3
#define P1_CHUNK 144
#define P1_NCH 25
#define P1_NRT 25        // 3600/144

// sim = dot/25.6 ; exp(sim) = exp2(dot * log2e/25.6)
#define C_EXP1 (0.0390625f * 1.4426950408889634f)
// exp(2*sim) = exp2(dot * 2*log2e/25.6)
#define C_EXP2 (0.0781250f * 1.4426950408889634f)

__global__ void cast_kernel(const float* __restrict__ a, const float* __restrict__ b,
                            f16* __restrict__ ah, f16* __restrict__ bh, int total8) {
  int i = blockIdx.x * blockDim.x + threadIdx.x;
  if (i >= total8) return;
  const float4* a4 = (const float4*)a;
  const float4* b4 = (const float4*)b;
  float4 x = a4[2 * (size_t)i], y = a4[2 * (size_t)i + 1];
  f16x8 o = {(f16)x.x, (f16)x.y, (f16)x.z, (f16)x.w,
             (f16)y.x, (f16)y.y, (f16)y.z, (f16)y.w};
  *(f16x8*)(ah + 8 * (size_t)i) = o;
  x = b4[2 * (size_t)i]; y = b4[2 * (size_t)i + 1];
  f16x8 o2 = {(f16)x.x, (f16)x.y, (f16)x.z, (f16)x.w,
              (f16)y.x, (f16)y.y, (f16)y.z, (f16)y.w};
  *(f16x8*)(bh + 8 * (size_t)i) = o2;
}

// Pass A: GEMM computing only the softmax denominators (no big store).
// D layout: col = s = lane&15, row = l = (lane>>4)*4+g. Barrier-free loop.
__global__ __launch_bounds__(P1_THREADS, 4) void gemm_stats_kernel(
    const f16* __restrict__ X, const f16* __restrict__ Y,
    float* __restrict__ den_r, float* __restrict__ den_c) {
  __shared__ float colsum_w[3][P1_CHUNK];
  const int rt = blockIdx.x, ch = blockIdx.y, n = blockIdx.z;
  const int tid = threadIdx.x;
  const int wave = tid >> 6, lane = tid & 63;
  const int q = lane >> 4, r = lane & 15;
  const int l0 = rt * P1_BM;
  const int s0 = ch * P1_CHUNK;

  // X row base pointers for this lane's 3 row-groups (fragments reloaded
  // per k from cache; NOT kept resident -- that killed occupancy).
  const f16* xrow0 = X + ((size_t)n * L_DIM + l0 + wave * 48 + 0 * 16 + r) * C_DIM + q * 8;
  const f16* xrow1 = xrow0 + 16 * C_DIM;
  const f16* xrow2 = xrow1 + 16 * C_DIM;

  float sum_e[3][4];
#pragma unroll
  for (int grp = 0; grp < 3; ++grp)
#pragma unroll
    for (int g = 0; g < 4; ++g) sum_e[grp][g] = 0.f;

  const f16* ybase = Y + ((size_t)n * S_DIM + s0) * C_DIM + q * 8;

  for (int it = 0; it < P1_ITERS; ++it) {
    f32x4 acc[3][3];  // [grp][nt]
#pragma unroll
    for (int grp = 0; grp < 3; ++grp)
#pragma unroll
      for (int nt = 0; nt < 3; ++nt) acc[grp][nt] = (f32x4){0.f, 0.f, 0.f, 0.f};

    // yb pipelined one k ahead; xa reloaded per k (L1-hot)
    f16x8 yb[3], ybn[3];
#pragma unroll
    for (int nt = 0; nt < 3; ++nt)
      yb[nt] = *(const f16x8*)(ybase + (size_t)(it * P1_BN + nt * 16 + r) * C_DIM);

#pragma unroll
    for (int k = 0; k < 8; ++k) {
      f16x8 xa[3];
      xa[0] = *(const f16x8*)(xrow0 + k * 32);
      xa[1] = *(const f16x8*)(xrow1 + k * 32);
      xa[2] = *(const f16x8*)(xrow2 + k * 32);
      if (k < 7) {
#pragma unroll
        for (int nt = 0; nt < 3; ++nt)
          ybn[nt] = *(const f16x8*)(ybase + (size_t)(it * P1_BN + nt * 16 + r) * C_DIM + (k + 1) * 32);
      }
#pragma unroll
      for (int nt = 0; nt < 3; ++nt)
#pragma unroll
        for (int grp = 0; grp < 3; ++grp)
          acc[grp][nt] = __builtin_amdgcn_mfma_f32_16x16x32_f16(xa[grp], yb[nt], acc[grp][nt], 0, 0, 0);
#pragma unroll
      for (int nt = 0; nt < 3; ++nt) yb[nt] = ybn[nt];
    }

    // epilogue: e = exp(sim); row sums in regs, col sums via q-shfl
#pragma unroll
    for (int nt = 0; nt < 3; ++nt) {
      float csum = 0.f;
#pragma unroll
      for (int grp = 0; grp < 3; ++grp) {
#pragma unroll
        for (int g = 0; g < 4; ++g) {
          float e = exp2f(acc[grp][nt][g] * C_EXP1);
          sum_e[grp][g] += e;
          csum += e;
        }
      }
      csum += __shfl_xor(csum, 16, 64);
      csum += __shfl_xor(csum, 32, 64);
      if (q == 0) colsum_w[wave][it * P1_BN + nt * 16 + r] = csum;
    }
  }

  // row sums: reduce over the 16 s-lanes
#pragma unroll
  for (int m = 1; m < 16; m <<= 1)
#pragma unroll
    for (int grp = 0; grp < 3; ++grp)
#pragma unroll
      for (int g = 0; g < 4; ++g) sum_e[grp][g] += __shfl_xor(sum_e[grp][g], m, 64);
  if (r == 0) {
#pragma unroll
    for (int grp = 0; grp < 3; ++grp)
#pragma unroll
      for (int g = 0; g < 4; ++g)
        atomicAdd(&den_r[n * L_DIM + l0 + wave * 48 + grp * 16 + q * 4 + g], sum_e[grp][g]);
  }

  __syncthreads();  // single barrier: merge per-wave col partials
  for (int i = tid; i < P1_CHUNK; i += P1_THREADS)
    atomicAdd(&den_c[n * S_DIM + s0 + i],
              colsum_w[0][i] + colsum_w[1][i] + colsum_w[2][i]);
}

__global__ void invert_kernel(float* __restrict__ a, float* __restrict__ b) {
  int i = blockIdx.x * blockDim.x + threadIdx.x;
  if (i >= N_B * L_DIM) return;
  a[i] = 1.0f / a[i];
  b[i] = 1.0f / b[i];
}

// Pass B: recompute GEMM with SWAPPED operands (D col=l=lane&15, row=s=q*4+g),
// write conf as nontemporal f32x4, fused row-argmax + colmax. Barrier-free.
__global__ __launch_bounds__(P1_THREADS, 4) void gemm_conf_kernel(
    const f16* __restrict__ X, const f16* __restrict__ Y,
    const float* __restrict__ invdr, const float* __restrict__ invdc,
    float* __restrict__ conf_out,
    unsigned long long* __restrict__ rowarg,
    unsigned int* __restrict__ colmax_bits) {
  __shared__ __attribute__((aligned(16))) float colmax_w[3][P1_CHUNK];
  const int rt = blockIdx.x, ch = blockIdx.y, n = blockIdx.z;
  const int tid = threadIdx.x;
  const int wave = tid >> 6, lane = tid & 63;
  const int q = lane >> 4, r = lane & 15;
  const int l0 = rt * P1_BM;
  const int s0 = ch * P1_CHUNK;

  const f16* xrow0 = X + ((size_t)n * L_DIM + l0 + wave * 48 + 0 * 16 + r) * C_DIM + q * 8;
  const f16* xrow1 = xrow0 + 16 * C_DIM;
  const f16* xrow2 = xrow1 + 16 * C_DIM;

  // this lane's row (l) per grp is l0 + wave*48 + grp*16 + r
  float idr[3];
#pragma unroll
  for (int grp = 0; grp < 3; ++grp)
    idr[grp] = invdr[n * L_DIM + l0 + wave * 48 + grp * 16 + r];

  // running row argmax; lane's s-values ascend over (it,nt,g) so strict >
  // keeps the smallest j.
  float mx[3];
  int mj[3];
#pragma unroll
  for (int i = 0; i < 3; ++i) { mx[i] = 0.f; mj[i] = 0; }

  float* cbase = conf_out + ((size_t)n * L_DIM + l0 + wave * 48) * S_DIM;
  const float* idcb = invdc + n * S_DIM + s0;
  const f16* ybase = Y + ((size_t)n * S_DIM + s0) * C_DIM + q * 8;

  for (int it = 0; it < P1_ITERS; ++it) {
    f32x4 acc[3][3];
#pragma unroll
    for (int grp = 0; grp < 3; ++grp)
#pragma unroll
      for (int nt = 0; nt < 3; ++nt) acc[grp][nt] = (f32x4){0.f, 0.f, 0.f, 0.f};

    f16x8 yb[3], ybn[3];
#pragma unroll
    for (int nt = 0; nt < 3; ++nt)
      yb[nt] = *(const f16x8*)(ybase + (size_t)(it * P1_BN + nt * 16 + r) * C_DIM);

#pragma unroll
    for (int k = 0; k < 8; ++k) {
      f16x8 xa[3];
      xa[0] = *(const f16x8*)(xrow0 + k * 32);
      xa[1] = *(const f16x8*)(xrow1 + k * 32);
      xa[2] = *(const f16x8*)(xrow2 + k * 32);
      if (k < 7) {
#pragma unroll
        for (int nt = 0; nt < 3; ++nt)
          ybn[nt] = *(const f16x8*)(ybase + (size_t)(it * P1_BN + nt * 16 + r) * C_DIM + (k + 1) * 32);
      }
#pragma unroll
      for (int nt = 0; nt < 3; ++nt)
#pragma unroll
        for (int grp = 0; grp < 3; ++grp)
          acc[grp][nt] = __builtin_amdgcn_mfma_f32_16x16x32_f16(yb[nt], xa[grp], acc[grp][nt], 0, 0, 0);
#pragma unroll
      for (int nt = 0; nt < 3; ++nt) yb[nt] = ybn[nt];
    }

    // D layout (swapped): col = l = r, row = s = q*4 + g.
#pragma unroll
    for (int nt = 0; nt < 3; ++nt) {
      const int lc = it * P1_BN + nt * 16 + q * 4;  // local s of this lane's 4
      const int sc = s0 + lc;
      const float4 idc4 = *(const float4*)(idcb + lc);
      f32x4 cmx = {0.f, 0.f, 0.f, 0.f};
#pragma unroll
      for (int grp = 0; grp < 3; ++grp) {
        f32x4 w;
        w.x = exp2f(acc[grp][nt][0] * C_EXP2) * (idc4.x * idr[grp]);
        w.y = exp2f(acc[grp][nt][1] * C_EXP2) * (idc4.y * idr[grp]);
        w.z = exp2f(acc[grp][nt][2] * C_EXP2) * (idc4.z * idr[grp]);
        w.w = exp2f(acc[grp][nt][3] * C_EXP2) * (idc4.w * idr[grp]);
        __builtin_nontemporal_store(w,
            (f32x4*)(cbase + (size_t)(grp * 16 + r) * S_DIM + sc));
        if (w.x > mx[grp]) { mx[grp] = w.x; mj[grp] = sc; }
        if (w.y > mx[grp]) { mx[grp] = w.y; mj[grp] = sc + 1; }
        if (w.z > mx[grp]) { mx[grp] = w.z; mj[grp] = sc + 2; }
        if (w.w > mx[grp]) { mx[grp] = w.w; mj[grp] = sc + 3; }
        cmx.x = fmaxf(cmx.x, w.x);
        cmx.y = fmaxf(cmx.y, w.y);
        cmx.z = fmaxf(cmx.z, w.z);
        cmx.w = fmaxf(cmx.w, w.w);
      }
      // colmax: reduce over the 16 l-lanes (lane bits 0-3)
#pragma unroll
      for (int m = 1; m < 16; m <<= 1) {
        cmx.x = fmaxf(cmx.x, __shfl_xor(cmx.x, m, 64));
        cmx.y = fmaxf(cmx.y, __shfl_xor(cmx.y, m, 64));
        cmx.z = fmaxf(cmx.z, __shfl_xor(cmx.z, m, 64));
        cmx.w = fmaxf(cmx.w, __shfl_xor(cmx.w, m, 64));
      }
      if (r == 0) *(f32x4*)&colmax_w[wave][lc] = cmx;
    }
  }

  // row argmax: reduce across the 4 q-lanes (lane bits 4-5)
#pragma unroll
  for (int m = 16; m < 64; m <<= 1) {
#pragma unroll
    for (int grp = 0; grp < 3; ++grp) {
      float ov = __shfl_xor(mx[grp], m, 64);
      int oj = __shfl_xor(mj[grp], m, 64);
      if (ov > mx[grp] || (ov == mx[grp] && oj < mj[grp])) { mx[grp] = ov; mj[grp] = oj; }
    }
  }
  if (q == 0) {
#pragma unroll
    for (int grp = 0; grp < 3; ++grp) {
      unsigned long long key =
          ((unsigned long long)__float_as_uint(mx[grp]) << 32) |
          (unsigned int)(~(unsigned int)mj[grp]);
      atomicMax(&rowarg[n * L_DIM + l0 + wave * 48 + grp * 16 + r], key);
    }
  }

  __syncthreads();  // single barrier: merge per-wave col partials
  for (int i = tid; i < P1_CHUNK; i += P1_THREADS) {
    float m3 = fmaxf(fmaxf(colmax_w[0][i], colmax_w[1][i]), colmax_w[2][i]);
    atomicMax(&colmax_bits[n * S_DIM + s0 + i], __float_as_uint(m3));
  }
}

__global__ void finalize_kernel(const unsigned long long* __restrict__ rowarg,
                                const float* __restrict__ colmax,
                                const int* __restrict__ h0c, const int* __restrict__ w0c,
                                const int* __restrict__ h1c, const int* __restrict__ w1c,
                                float* __restrict__ out_maskv, float* __restrict__ out_jids,
                                float* __restrict__ out_mconf) {
  int i = blockIdx.x * blockDim.x + threadIdx.x;
  if (i >= N_B * L_DIM) return;
  int n = i / L_DIM, l = i - n * L_DIM;
  unsigned long long key = rowarg[i];
  float rm = __uint_as_float((unsigned int)(key >> 32));
  int j = (int)(~(unsigned int)key);
  int W0 = *w0c, H0 = *h0c, W1 = *w1c, H1 = *h1c;
  int li = l / W0, lj = l - li * W0;
  bool vl = (li >= 2) && (li < H0 - 2) && (lj >= 2) && (lj < W0 - 2);
  int si = j / W1, sj = j - si * W1;
  bool vs = (si >= 2) && (si < H1 - 2) && (sj >= 2) && (sj < W1 - 2);
  float cm = colmax[n * S_DIM + j];
  bool mv = (rm > 0.2f) && vl && vs &&
            (__float_as_uint(rm) == __float_as_uint(cm));
  out_maskv[i] = mv ? 1.0f : 0.0f;
  out_jids[i]  = mv ? (float)j : 0.0f;
  out_mconf[i] = mv ? rm : 0.0f;
}

extern "C" void kernel_launch(void* const* d_in, const int* in_sizes, int n_in,
                              void* d_out, int out_size, void* d_ws, size_t ws_size,
                              hipStream_t stream) {
  const float* f0 = (const float*)d_in[0];
  const float* f1 = (const float*)d_in[1];
  const int* h0c = (const int*)d_in[2];
  const int* w0c = (const int*)d_in[3];
  const int* h1c = (const int*)d_in[4];
  const int* w1c = (const int*)d_in[5];

  char* ws = (char*)d_ws;
  size_t o = 0;
  f16* f0h = (f16*)(ws + o);               o += (size_t)N_B * L_DIM * C_DIM * 2;   // 7.37MB
  f16* f1h = (f16*)(ws + o);               o += (size_t)N_B * S_DIM * C_DIM * 2;   // 7.37MB
  // zeroed region (one memset): den_r | den_c | rowarg | colmax
  float* den_r = (float*)(ws + o);         o += (size_t)N_B * L_DIM * 4;
  float* den_c = (float*)(ws + o);         o += (size_t)N_B * S_DIM * 4;
  unsigned long long* rowarg = (unsigned long long*)(ws + o); o += (size_t)N_B * L_DIM * 8;
  float* colmax = (float*)(ws + o);        o += (size_t)N_B * S_DIM * 4;
  size_t zero_bytes = (size_t)N_B * (L_DIM * 4 + S_DIM * 4 + L_DIM * 8 + S_DIM * 4);

  float* conf = (float*)d_out;
  float* out_maskv = conf + (size_t)N_B * L_DIM * S_DIM;
  float* out_jids = out_maskv + N_B * L_DIM;
  float* out_mconf = out_jids + N_B * L_DIM;

  hipMemsetAsync(den_r, 0, zero_bytes, stream);

  int total8 = N_B * L_DIM * C_DIM / 8;  // 460800
  cast_kernel<<<dim3((total8 + 255) / 256), 256, 0, stream>>>(f0, f1, f0h, f1h, total8);

  dim3 g1(P1_NRT, P1_NCH, N_B);  // 25 x 25 x 4 = 2500 blocks
  gemm_stats_kernel<<<g1, P1_THREADS, 0, stream>>>(f0h, f1h, den_r, den_c);
  invert_kernel<<<(N_B * L_DIM + 255) / 256, 256, 0, stream>>>(den_r, den_c);
  gemm_conf_kernel<<<g1, P1_THREADS, 0, stream>>>(
      f0h, f1h, den_r, den_c, conf, rowarg, (unsigned int*)colmax);
  finalize_kernel<<<(N_B * L_DIM + 255) / 256, 256, 0, stream>>>(
      rowarg, colmax, h0c, w0c, h1c, w1c, out_maskv, out_jids, out_mconf);
}

// Round 6
// 517.197 us; speedup vs baseline: 1.0277x; 1.0277x over previous
//
#include <hip/hip_runtime.h>
#include <stdint.h>

// CoarseMatching on MI355X, round 8.
// conf[n,l,s] = softmax_l(sim)*softmax_s(sim), sim = <f0[l],f1[s]>/25.6.
// Round-8: revert to the store-e topology (round 0), with both passes fixed.
// Round-5 evidence: GEMM-recompute pass B self-thrashes -- the 207MB conf
// stream flushes L2/L3 so operand re-reads (1.1GB L2-side) miss to HBM
// (FETCH 280MB/pass). Storing e (104MB) and streaming it back is cheaper.
//  Pass A: GEMM, X-resident regs, LDS-staged Y, SWAPPED mfma operands so
//    each lane owns 4 consecutive s -> f16x4 e-stores (was 36 scalar f16),
//    den_r via q-lane reduce, den_c via r-lane reduce. grid 25x15x4.
//  Pass B: pure stream: conf = e^2*idr*idc (no exp), one WAVE per row ->
//    rowarg plain store (no atomic), colmax in 15 f32x4 regs -> LDS bits
//    atomicMax -> one global atomicMax per col per block. 900 blocks.

typedef _Float16 f16;
typedef _Float16 f16x8 __attribute__((ext_vector_type(8)));
typedef _Float16 f16x4 __attribute__((ext_vector_type(4)));
typedef float f32x4 __attribute__((ext_vector_type(4)));

#define N_B 4
#define L_DIM 3600
#define S_DIM 3600
#define C_DIM 256

// Pass A tiling: 3 waves x 48 rows = 144 rows/block; 48 cols/iter;
// 240-col chunks. grid 25 x 15 x 4 = 1500 blocks.
#define P1_THREADS 192
#define P1_BM 144
#define P1_BN 48
#define P1_ITERS 5
#define P1_CHUNK 240
#define P1_NCH 15
#define P1_NRT 25        // 3600/144
#define YT_STRIDE 264    // 256 + 8 halfs pad

// Pass B: 16 rows/block (4 waves x 4 rows), grid 225 x 4.
#define PB_ROWS 16

// sim = dot/25.6 ; exp(sim) = exp2(dot * log2e/25.6)
#define C_EXP1 (0.0390625f * 1.4426950408889634f)

__global__ void cast_kernel(const float* __restrict__ a, const float* __restrict__ b,
                            f16* __restrict__ ah, f16* __restrict__ bh, int total8) {
  int i = blockIdx.x * blockDim.x + threadIdx.x;
  if (i >= total8) return;
  const float4* a4 = (const float4*)a;
  const float4* b4 = (const float4*)b;
  float4 x = a4[2 * (size_t)i], y = a4[2 * (size_t)i + 1];
  f16x8 o = {(f16)x.x, (f16)x.y, (f16)x.z, (f16)x.w,
             (f16)y.x, (f16)y.y, (f16)y.z, (f16)y.w};
  *(f16x8*)(ah + 8 * (size_t)i) = o;
  x = b4[2 * (size_t)i]; y = b4[2 * (size_t)i + 1];
  f16x8 o2 = {(f16)x.x, (f16)x.y, (f16)x.z, (f16)x.w,
              (f16)y.x, (f16)y.y, (f16)y.z, (f16)y.w};
  *(f16x8*)(bh + 8 * (size_t)i) = o2;
}

// Pass A: fused GEMM -> e=exp(sim) f16 store + den_r + den_c.
// Swapped mfma: D element (lane,g) = sim[l = grp*16+r][s = it*48+nt*16+q*4+g].
__global__ __launch_bounds__(P1_THREADS, 2) void gemm_stats_e_kernel(
    const f16* __restrict__ X, const f16* __restrict__ Y,
    f16* __restrict__ eh, float* __restrict__ den_r, float* __restrict__ den_c) {
  __shared__ f16 Yt[P1_BN][YT_STRIDE];
  __shared__ __attribute__((aligned(16))) float colsum_w[3][P1_CHUNK];
  const int rt = blockIdx.x, ch = blockIdx.y, n = blockIdx.z;
  const int tid = threadIdx.x;
  const int wave = tid >> 6, lane = tid & 63;
  const int q = lane >> 4, r = lane & 15;
  const int l0 = rt * P1_BM;
  const int s0 = ch * P1_CHUNK;

  // X fragments resident: 48 rows (3 groups of 16) x K=256.
  f16x8 a[3][8];
#pragma unroll
  for (int grp = 0; grp < 3; ++grp) {
    const f16* xrow = X + ((size_t)n * L_DIM + l0 + wave * 48 + grp * 16 + r) * C_DIM;
#pragma unroll
    for (int k = 0; k < 8; ++k) a[grp][k] = *(const f16x8*)(xrow + k * 32 + q * 8);
  }

  float prs[3];  // per-lane den_r partials (row l = grp*16+r)
#pragma unroll
  for (int grp = 0; grp < 3; ++grp) prs[grp] = 0.f;

  f16* ebase = eh + ((size_t)n * L_DIM + l0 + wave * 48) * S_DIM;

  for (int it = 0; it < P1_ITERS; ++it) {
    const f16* ysrc = Y + ((size_t)n * S_DIM + s0 + it * P1_BN) * C_DIM;
#pragma unroll
    for (int i = 0; i < 8; ++i) {  // 48*32=1536 16B chunks, 192 thr x 8
      int c = i * P1_THREADS + tid;
      int row = c >> 5, cc = c & 31;
      *(f16x8*)&Yt[row][cc * 8] = *(const f16x8*)(ysrc + row * C_DIM + cc * 8);
    }
    __syncthreads();

    f32x4 acc[3][3];  // [grp][nt]
#pragma unroll
    for (int grp = 0; grp < 3; ++grp)
#pragma unroll
      for (int nt = 0; nt < 3; ++nt) acc[grp][nt] = (f32x4){0.f, 0.f, 0.f, 0.f};

#pragma unroll
    for (int k = 0; k < 8; ++k) {
#pragma unroll
      for (int nt = 0; nt < 3; ++nt) {
        f16x8 b = *(const f16x8*)&Yt[nt * 16 + r][k * 32 + q * 8];
#pragma unroll
        for (int grp = 0; grp < 3; ++grp)
          acc[grp][nt] = __builtin_amdgcn_mfma_f32_16x16x32_f16(b, a[grp][k], acc[grp][nt], 0, 0, 0);
      }
    }
    __syncthreads();

    // epilogue: lane owns rows l=grp*16+r, cols s=it*48+nt*16+q*4+{0..3}
#pragma unroll
    for (int nt = 0; nt < 3; ++nt) {
      const int sl = it * P1_BN + nt * 16 + q * 4;  // local s base
      f32x4 c4 = (f32x4){0.f, 0.f, 0.f, 0.f};
#pragma unroll
      for (int grp = 0; grp < 3; ++grp) {
        f32x4 e4;
        e4.x = exp2f(acc[grp][nt][0] * C_EXP1);
        e4.y = exp2f(acc[grp][nt][1] * C_EXP1);
        e4.z = exp2f(acc[grp][nt][2] * C_EXP1);
        e4.w = exp2f(acc[grp][nt][3] * C_EXP1);
        f16x4 h = {(f16)e4.x, (f16)e4.y, (f16)e4.z, (f16)e4.w};
        *(f16x4*)(ebase + (size_t)(grp * 16 + r) * S_DIM + s0 + sl) = h;
        prs[grp] += e4.x + e4.y + e4.z + e4.w;
        c4.x += e4.x; c4.y += e4.y; c4.z += e4.z; c4.w += e4.w;
      }
      // den_c partials: reduce over the 16 l-lanes (lane bits 0-3)
#pragma unroll
      for (int m = 1; m < 16; m <<= 1) {
        c4.x += __shfl_xor(c4.x, m, 64);
        c4.y += __shfl_xor(c4.y, m, 64);
        c4.z += __shfl_xor(c4.z, m, 64);
        c4.w += __shfl_xor(c4.w, m, 64);
      }
      if (r == 0) *(f32x4*)&colsum_w[wave][sl] = c4;
    }
  }

  // den_r: reduce over the 4 q-lanes (lane bits 4-5)
#pragma unroll
  for (int m = 16; m < 64; m <<= 1)
#pragma unroll
    for (int grp = 0; grp < 3; ++grp) prs[grp] += __shfl_xor(prs[grp], m, 64);
  if (q == 0) {
#pragma unroll
    for (int grp = 0; grp < 3; ++grp)
      atomicAdd(&den_r[n * L_DIM + l0 + wave * 48 + grp * 16 + r], prs[grp]);
  }

  __syncthreads();
  for (int i = tid; i < P1_CHUNK; i += P1_THREADS)
    atomicAdd(&den_c[n * S_DIM + s0 + i],
              colsum_w[0][i] + colsum_w[1][i] + colsum_w[2][i]);
}

__global__ void invert_kernel(float* __restrict__ a, float* __restrict__ b) {
  int i = blockIdx.x * blockDim.x + threadIdx.x;
  if (i >= N_B * L_DIM) return;
  a[i] = 1.0f / a[i];
  b[i] = 1.0f / b[i];
}

// Pass B: streaming. conf = e^2*idr*idc. One wave per row: rowarg plain
// store; colmax in 15 f32x4 regs -> LDS bits atomicMax -> global atomicMax.
__global__ __launch_bounds__(256, 4) void conf_stream_kernel(
    const f16* __restrict__ eh, const float* __restrict__ invdr,
    const float* __restrict__ invdc, float* __restrict__ conf_out,
    unsigned long long* __restrict__ rowarg,
    unsigned int* __restrict__ colmax_bits) {
  __shared__ unsigned cmx_lds[S_DIM];
  const int n = blockIdx.y;
  const int l0 = blockIdx.x * PB_ROWS;
  const int tid = threadIdx.x, wave = tid >> 6, lane = tid & 63;

  for (int i = tid; i < S_DIM; i += 256) cmx_lds[i] = 0u;
  __syncthreads();

  f32x4 cm[15];
#pragma unroll
  for (int c = 0; c < 15; ++c) cm[c] = (f32x4){0.f, 0.f, 0.f, 0.f};

  const float* idcb = invdc + (size_t)n * S_DIM;

  for (int rr = 0; rr < 4; ++rr) {
    const int l = l0 + wave * 4 + rr;
    const float idr = invdr[n * L_DIM + l];
    const f16* erow = eh + ((size_t)n * L_DIM + l) * S_DIM;
    float* crow = conf_out + ((size_t)n * L_DIM + l) * S_DIM;
    float mx = 0.f;
    int mj = 0;
#pragma unroll
    for (int c = 0; c < 15; ++c) {
      if (c < 14 || lane < 4) {  // tail chunk: 3600-14*256=16 cols, lanes 0-3
        const int col = c * 256 + lane * 4;
        f16x4 e4 = *(const f16x4*)(erow + col);
        const float4 idc4 = *(const float4*)(idcb + col);
        f32x4 w;
        w.x = (float)e4.x * (float)e4.x * idr * idc4.x;
        w.y = (float)e4.y * (float)e4.y * idr * idc4.y;
        w.z = (float)e4.z * (float)e4.z * idr * idc4.z;
        w.w = (float)e4.w * (float)e4.w * idr * idc4.w;
        __builtin_nontemporal_store(w, (f32x4*)(crow + col));
        if (w.x > mx) { mx = w.x; mj = col; }
        if (w.y > mx) { mx = w.y; mj = col + 1; }
        if (w.z > mx) { mx = w.z; mj = col + 2; }
        if (w.w > mx) { mx = w.w; mj = col + 3; }
        cm[c].x = fmaxf(cm[c].x, w.x);
        cm[c].y = fmaxf(cm[c].y, w.y);
        cm[c].z = fmaxf(cm[c].z, w.z);
        cm[c].w = fmaxf(cm[c].w, w.w);
      }
    }
    // row argmax across 64 lanes; larger mx wins, tie -> smaller mj
#pragma unroll
    for (int m = 1; m < 64; m <<= 1) {
      float ov = __shfl_xor(mx, m, 64);
      int oj = __shfl_xor(mj, m, 64);
      if (ov > mx || (ov == mx && oj < mj)) { mx = ov; mj = oj; }
    }
    if (lane == 0) {
      unsigned long long key =
          ((unsigned long long)__float_as_uint(mx) << 32) |
          (unsigned int)(~(unsigned int)mj);
      rowarg[n * L_DIM + l] = key;  // wave owns the row: plain store
    }
  }

  // merge per-lane colmax regs into LDS (bits compare == float compare, >0)
#pragma unroll
  for (int c = 0; c < 15; ++c) {
    if (c < 14 || lane < 4) {
      const int col = c * 256 + lane * 4;
      atomicMax(&cmx_lds[col + 0], __float_as_uint(cm[c].x));
      atomicMax(&cmx_lds[col + 1], __float_as_uint(cm[c].y));
      atomicMax(&cmx_lds[col + 2], __float_as_uint(cm[c].z));
      atomicMax(&cmx_lds[col + 3], __float_as_uint(cm[c].w));
    }
  }
  __syncthreads();
  for (int i = tid; i < S_DIM; i += 256)
    atomicMax(&colmax_bits[(size_t)n * S_DIM + i], cmx_lds[i]);
}

__global__ void finalize_kernel(const unsigned long long* __restrict__ rowarg,
                                const float* __restrict__ colmax,
                                const int* __restrict__ h0c, const int* __restrict__ w0c,
                                const int* __restrict__ h1c, const int* __restrict__ w1c,
                                float* __restrict__ out_maskv, float* __restrict__ out_jids,
                                float* __restrict__ out_mconf) {
  int i = blockIdx.x * blockDim.x + threadIdx.x;
  if (i >= N_B * L_DIM) return;
  int n = i / L_DIM, l = i - n * L_DIM;
  unsigned long long key = rowarg[i];
  float rm = __uint_as_float((unsigned int)(key >> 32));
  int j = (int)(~(unsigned int)key);
  int W0 = *w0c, H0 = *h0c, W1 = *w1c, H1 = *h1c;
  int li = l / W0, lj = l - li * W0;
  bool vl = (li >= 2) && (li < H0 - 2) && (lj >= 2) && (lj < W0 - 2);
  int si = j / W1, sj = j - si * W1;
  bool vs = (si >= 2) && (si < H1 - 2) && (sj >= 2) && (sj < W1 - 2);
  float cm = colmax[n * S_DIM + j];
  bool mv = (rm > 0.2f) && vl && vs &&
            (__float_as_uint(rm) == __float_as_uint(cm));
  out_maskv[i] = mv ? 1.0f : 0.0f;
  out_jids[i]  = mv ? (float)j : 0.0f;
  out_mconf[i] = mv ? rm : 0.0f;
}

extern "C" void kernel_launch(void* const* d_in, const int* in_sizes, int n_in,
                              void* d_out, int out_size, void* d_ws, size_t ws_size,
                              hipStream_t stream) {
  const float* f0 = (const float*)d_in[0];
  const float* f1 = (const float*)d_in[1];
  const int* h0c = (const int*)d_in[2];
  const int* w0c = (const int*)d_in[3];
  const int* h1c = (const int*)d_in[4];
  const int* w1c = (const int*)d_in[5];

  char* ws = (char*)d_ws;
  size_t o = 0;
  f16* f0h = (f16*)(ws + o);               o += (size_t)N_B * L_DIM * C_DIM * 2;   // 7.37MB
  f16* f1h = (f16*)(ws + o);               o += (size_t)N_B * S_DIM * C_DIM * 2;   // 7.37MB
  // zeroed region (one memset): den_r | den_c | colmax
  float* den_r = (float*)(ws + o);         o += (size_t)N_B * L_DIM * 4;
  float* den_c = (float*)(ws + o);         o += (size_t)N_B * S_DIM * 4;
  float* colmax = (float*)(ws + o);        o += (size_t)N_B * S_DIM * 4;
  size_t zero_bytes = (size_t)N_B * (L_DIM * 4 + S_DIM * 4 + S_DIM * 4);
  unsigned long long* rowarg = (unsigned long long*)(ws + o); o += (size_t)N_B * L_DIM * 8;
  f16* eh = (f16*)(ws + o);                o += (size_t)N_B * L_DIM * S_DIM * 2;   // 103.7MB

  float* conf = (float*)d_out;
  float* out_maskv = conf + (size_t)N_B * L_DIM * S_DIM;
  float* out_jids = out_maskv + N_B * L_DIM;
  float* out_mconf = out_jids + N_B * L_DIM;

  hipMemsetAsync(den_r, 0, zero_bytes, stream);

  int total8 = N_B * L_DIM * C_DIM / 8;  // 460800
  cast_kernel<<<dim3((total8 + 255) / 256), 256, 0, stream>>>(f0, f1, f0h, f1h, total8);

  dim3 g1(P1_NRT, P1_NCH, N_B);  // 25 x 15 x 4 = 1500 blocks
  gemm_stats_e_kernel<<<g1, P1_THREADS, 0, stream>>>(f0h, f1h, eh, den_r, den_c);
  invert_kernel<<<(N_B * L_DIM + 255) / 256, 256, 0, stream>>>(den_r, den_c);
  dim3 g2(L_DIM / PB_ROWS, N_B);  // 225 x 4 = 900 blocks
  conf_stream_kernel<<<g2, 256, 0, stream>>>(
      eh, den_r, den_c, conf, rowarg, (unsigned int*)colmax);
  finalize_kernel<<<(N_B * L_DIM + 255) / 256, 256, 0, stream>>>(
      rowarg, colmax, h0c, w0c, h1c, w1c, out_maskv, out_jids, out_mconf);
}